// Round 17
// baseline (34.359 us; speedup 1.0000x reference)
//
#include <hip/hip_runtime.h>
#include <math.h>

#define D 40
#define NN 1024
#define BB 2

typedef __attribute__((ext_vector_type(8))) _Float16 f16x8;
typedef __attribute__((ext_vector_type(4))) float f32x4;

__device__ __forceinline__ unsigned int pk16(float a, float b) {
    return __builtin_bit_cast(unsigned int, __builtin_amdgcn_cvt_pkrtz(a, b));
}

// gelu = a - a/(exp2(a*(c1*a^2+c0))+1); 5 VALU + 2 trans
__device__ __forceinline__ float gelu_tanh(float a) {
    float u = a * a;
    float t1 = fmaf(0.10294366f, u, 2.3022083f);
    float e = __builtin_amdgcn_exp2f(a * t1);
    float r = __builtin_amdgcn_rcpf(e + 1.0f);
    return fmaf(-a, r, a);
}

// anti-remat pins
__device__ __forceinline__ void pinf(float& x) { asm volatile("" : "+v"(x)); }
__device__ __forceinline__ void pin4(float4& v) {
    asm volatile("" : "+v"(v.x), "+v"(v.y), "+v"(v.z), "+v"(v.w));
}
__device__ __forceinline__ void pin8(f16x8& v) {
    uint4 u = __builtin_bit_cast(uint4, v);
    asm volatile("" : "+v"(u.x), "+v"(u.y), "+v"(u.z), "+v"(u.w));
    v = __builtin_bit_cast(f16x8, u);
}

// build fp16x8 B-fragment: gelu(air + ajv) for 8 consecutive k
__device__ __forceinline__ f16x8 frag8(float4 a0, float4 a1, float4 x0, float4 x1) {
    float g0 = gelu_tanh(a0.x + x0.x);
    float g1 = gelu_tanh(a0.y + x0.y);
    float g2 = gelu_tanh(a0.z + x0.z);
    float g3 = gelu_tanh(a0.w + x0.w);
    float g4 = gelu_tanh(a1.x + x1.x);
    float g5 = gelu_tanh(a1.y + x1.y);
    float g6 = gelu_tanh(a1.z + x1.z);
    float g7 = gelu_tanh(a1.w + x1.w);
    return __builtin_bit_cast(f16x8,
        make_uint4(pk16(g0, g1), pk16(g2, g3), pk16(g4, g5), pk16(g6, g7)));
}

// ai = x @ W1[:D] + b1, aj = x @ W1[D:].  2 rows/block; one 40-FMA chain/thread.
__global__ __launch_bounds__(256) void precompute_kernel(
    const float* __restrict__ x, const float* __restrict__ W1,
    const float* __restrict__ b1, const float* __restrict__ W2,
    float* __restrict__ ai, float* __restrict__ aj, uint4* __restrict__ w2fT) {
    const int t = threadIdx.x;
    const int bid = blockIdx.x;
    const int r = (bid << 1) + (t >> 7);
    const int tl = t & 127;
    const float* xr = x + (size_t)r * D;

    if (tl < D) {
        const int d = tl;
        float s = b1[d];
#pragma unroll
        for (int k = 0; k < D; ++k) s = fmaf(xr[k], W1[k * D + d], s);
        ai[(size_t)r * D + d] = s;
    } else if (tl >= 64 && tl < 64 + D) {
        const int d = tl - 64;
        float s = 0.0f;
#pragma unroll
        for (int k = 0; k < D; ++k) s = fmaf(xr[k], W1[(D + k) * D + d], s);
        aj[(size_t)r * D + d] = s;
    }

    if (bid == 0 && t < 64) {
        // A = W2^T: A[m=d, k] = W2[k][d]; lane: m = l&15, k = kt*32 + (l>>4)*8 + e
        const int lr = t & 15, lg = t >> 4;
#pragma unroll
        for (int mt = 0; mt < 3; ++mt)
#pragma unroll
            for (int kt = 0; kt < 2; ++kt) {
                unsigned int u[4];
#pragma unroll
                for (int pe = 0; pe < 4; ++pe) {
                    int k0 = kt * 32 + lg * 8 + pe * 2;
                    int dd = mt * 16 + lr;
                    float v0 = (k0 < D && dd < D) ? W2[k0 * D + dd] : 0.0f;
                    float v1 = (k0 + 1 < D && dd < D) ? W2[(k0 + 1) * D + dd] : 0.0f;
                    u[pe] = pk16(v0, v1);
                }
                w2fT[(mt * 2 + kt) * 64 + t] = make_uint4(u[0], u[1], u[2], u[3]);
            }
    }
}

__global__ __launch_bounds__(256)
__attribute__((amdgpu_waves_per_eu(3)))     // min 3 waves/EU: VGPR budget <= ~168
void pair_kernel(
    const float* __restrict__ ai_g, const float* __restrict__ aj_g,
    const uint4* __restrict__ w2fT, const float* __restrict__ b2,
    float* __restrict__ out) {
    __shared__ float mbuf[224];               // 4 waves x 56 (only LDS use)

    const int t = threadIdx.x;
    const int bid = blockIdx.x;
    const int bb = bid & 1;
    const int i = NN - 1 - (bid >> 1);        // big rows first
    const int w = t >> 6;
    const int l = t & 63;
    const int lr = l & 15;
    const int lg = l >> 4;                    // 0..3
    const int idxA = lr << 2;

    // W2^T A-fragments (zero rows for k>=40 kill don't-care B slots), pinned
    f16x8 w2t[3][2];
#pragma unroll
    for (int mt = 0; mt < 3; ++mt)
#pragma unroll
        for (int kt = 0; kt < 2; ++kt) {
            w2t[mt][kt] = __builtin_bit_cast(f16x8, w2fT[(mt * 2 + kt) * 64 + l]);
            pin8(w2t[mt][kt]);
        }

    // bias for d = mt*16 + lg*4 + r (0 for d >= 40), pinned
    float bv2[3][4];
#pragma unroll
    for (int mt = 0; mt < 3; ++mt)
#pragma unroll
        for (int r = 0; r < 4; ++r) {
            int d = mt * 16 + lg * 4 + r;
            bv2[mt][r] = (d < D) ? b2[d] : 0.0f;
            pinf(bv2[mt][r]);
        }

    const float* ai_row = ai_g + ((size_t)bb * NN + i) * D;
    float4 air0 = *reinterpret_cast<const float4*>(ai_row + (lg << 3));
    float4 air1 = *reinterpret_cast<const float4*>(ai_row + (lg << 3) + 4);
    float4 ai32 = *reinterpret_cast<const float4*>(ai_row + 32 + ((l >> 5) << 2));
    pin4(air0); pin4(air1); pin4(ai32);

    const float* aj_b = aj_g + (size_t)bb * NN * D;

    // no-max softmax state: s <= ~20 so w = e^s is f32-safe (bit-validated R13-R16)
    float l_run = 0.0f;
    float o[3][4];
#pragma unroll
    for (int mt = 0; mt < 3; ++mt)
#pragma unroll
        for (int r = 0; r < 4; ++r) o[mt][r] = 0.0f;

    auto window = [&](int jbase, float4 qa0, float4 qa1, float4 qb0,
                      float4 qb1, float4 qt, bool masked) {
        // tail gelu: k = 32+kk..+3 (kk=(l>>5)*4) of j = jbase+(l&31)
        unsigned int pd0, pd1;
        {
            float g0 = gelu_tanh(ai32.x + qt.x);
            float g1 = gelu_tanh(ai32.y + qt.y);
            float g2 = gelu_tanh(ai32.z + qt.z);
            float g3 = gelu_tanh(ai32.w + qt.w);
            pd0 = pk16(g0, g1);
            pd1 = pk16(g2, g3);
        }
        uint4 tB0, tB1;
        tB0.x = __builtin_amdgcn_ds_bpermute(idxA,       pd0);
        tB0.y = __builtin_amdgcn_ds_bpermute(idxA,       pd1);
        tB0.z = __builtin_amdgcn_ds_bpermute(idxA + 128, pd0);
        tB0.w = __builtin_amdgcn_ds_bpermute(idxA + 128, pd1);
        tB1.x = __builtin_amdgcn_ds_bpermute(idxA + 64,  pd0);
        tB1.y = __builtin_amdgcn_ds_bpermute(idxA + 64,  pd1);
        tB1.z = __builtin_amdgcn_ds_bpermute(idxA + 192, pd0);
        tB1.w = __builtin_amdgcn_ds_bpermute(idxA + 192, pd1);

        f32x4 acc[3][2];
#pragma unroll
        for (int mt = 0; mt < 3; ++mt)
#pragma unroll
            for (int n = 0; n < 2; ++n)
                acc[mt][n] = (f32x4){bv2[mt][0], bv2[mt][1], bv2[mt][2], bv2[mt][3]};
        {
            f16x8 B = frag8(air0, air1, qa0, qa1);
            f16x8 Bt = __builtin_bit_cast(f16x8, tB0);
#pragma unroll
            for (int mt = 0; mt < 3; ++mt) {
                acc[mt][0] = __builtin_amdgcn_mfma_f32_16x16x32_f16(
                    w2t[mt][0], B, acc[mt][0], 0, 0, 0);
                acc[mt][0] = __builtin_amdgcn_mfma_f32_16x16x32_f16(
                    w2t[mt][1], Bt, acc[mt][0], 0, 0, 0);
            }
        }
        {
            f16x8 B = frag8(air0, air1, qb0, qb1);
            f16x8 Bt = __builtin_bit_cast(f16x8, tB1);
#pragma unroll
            for (int mt = 0; mt < 3; ++mt) {
                acc[mt][1] = __builtin_amdgcn_mfma_f32_16x16x32_f16(
                    w2t[mt][0], B, acc[mt][1], 0, 0, 0);
                acc[mt][1] = __builtin_amdgcn_mfma_f32_16x16x32_f16(
                    w2t[mt][1], Bt, acc[mt][1], 0, 0, 0);
            }
        }

        // ||p|| per j; w = e^s directly (no max shift, no rescale)
        float sv[2];
#pragma unroll
        for (int n = 0; n < 2; ++n) {
            float sq = 0.0f;
#pragma unroll
            for (int mt = 0; mt < 3; ++mt)
#pragma unroll
                for (int r = 0; r < 4; ++r)
                    sq = fmaf(acc[mt][n][r], acc[mt][n][r], sq);
            sq += __shfl_xor(sq, 16);
            sq += __shfl_xor(sq, 32);
            if (masked) {
                int j = jbase + n * 16 + lr;
                sv[n] = (j <= i) ? __builtin_amdgcn_sqrtf(sq) : -1e30f;
            } else {
                sv[n] = __builtin_amdgcn_sqrtf(sq);
            }
        }
        float w0 = __expf(sv[0]);              // masked j -> exactly 0
        float w1 = __expf(sv[1]);
        l_run += w0 + w1;
#pragma unroll
        for (int mt = 0; mt < 3; ++mt)
#pragma unroll
            for (int r = 0; r < 4; ++r)
                o[mt][r] = fmaf(w0, acc[mt][0][r], fmaf(w1, acc[mt][1][r], o[mt][r]));
    };

    // ---- unrolled-by-2 full windows: both windows' loads issued up front ----
    int jbase = w << 5;
    const float* pA = aj_b + (size_t)(jbase + lr) * D + (lg << 3);
    const float* pT = aj_b + (size_t)(jbase + (l & 31)) * D + 32 + ((l >> 5) << 2);
    for (; jbase + 159 <= i; jbase += 256) {
        float4 Aa0 = *reinterpret_cast<const float4*>(pA);
        float4 Aa1 = *reinterpret_cast<const float4*>(pA + 4);
        float4 Ab0 = *reinterpret_cast<const float4*>(pA + 16 * D);
        float4 Ab1 = *reinterpret_cast<const float4*>(pA + 16 * D + 4);
        float4 At  = *reinterpret_cast<const float4*>(pT);
        float4 Ba0 = *reinterpret_cast<const float4*>(pA + 128 * D);
        float4 Ba1 = *reinterpret_cast<const float4*>(pA + 128 * D + 4);
        float4 Bb0 = *reinterpret_cast<const float4*>(pA + 144 * D);
        float4 Bb1 = *reinterpret_cast<const float4*>(pA + 144 * D + 4);
        float4 Bt  = *reinterpret_cast<const float4*>(pT + 128 * D);
        pA += 256 * D;
        pT += 256 * D;
        window(jbase, Aa0, Aa1, Ab0, Ab1, At, false);
        window(jbase + 128, Ba0, Ba1, Bb0, Bb1, Bt, false);
    }
    // ---- remainder (<= 2 windows): clamped loads, masked sv (bit-identical) ----
    for (; jbase <= i; jbase += 128) {
        const int j0 = min(jbase + lr, i);
        const int j1 = min(jbase + 16 + lr, i);
        const int jt = min(jbase + (l & 31), i);
        const float* r0 = aj_b + (size_t)j0 * D + (lg << 3);
        const float* r1 = aj_b + (size_t)j1 * D + (lg << 3);
        float4 qa0 = *reinterpret_cast<const float4*>(r0);
        float4 qa1 = *reinterpret_cast<const float4*>(r0 + 4);
        float4 qb0 = *reinterpret_cast<const float4*>(r1);
        float4 qb1 = *reinterpret_cast<const float4*>(r1 + 4);
        float4 qt  = *reinterpret_cast<const float4*>(
            aj_b + (size_t)jt * D + 32 + ((l >> 5) << 2));
        window(jbase, qa0, qa1, qb0, qb1, qt, true);
    }

    // ---- reduce o over the 16 j-lanes, merge 4 waves ----
#pragma unroll
    for (int mt = 0; mt < 3; ++mt)
#pragma unroll
        for (int r = 0; r < 4; ++r) {
            float v = o[mt][r];
            v += __shfl_xor(v, 1);
            v += __shfl_xor(v, 2);
            v += __shfl_xor(v, 4);
            v += __shfl_xor(v, 8);
            o[mt][r] = v;
        }
    l_run += __shfl_xor(l_run, 1);
    l_run += __shfl_xor(l_run, 2);
    l_run += __shfl_xor(l_run, 4);
    l_run += __shfl_xor(l_run, 8);

    if (lr == 0) {
#pragma unroll
        for (int mt = 0; mt < 3; ++mt)
#pragma unroll
            for (int r = 0; r < 4; ++r) {
                int d = mt * 16 + lg * 4 + r;
                if (d < D) mbuf[w * 56 + d] = o[mt][r];
            }
        if (lg == 0) mbuf[w * 56 + 48] = l_run;
    }
    __syncthreads();
    if (t < D) {
        float L = mbuf[48] + mbuf[56 + 48] + mbuf[112 + 48] + mbuf[168 + 48];
        float val = mbuf[t] + mbuf[56 + t] + mbuf[112 + t] + mbuf[168 + t];
        out[((size_t)bb * NN + i) * D + t] = val / L;
    }
}

extern "C" void kernel_launch(void* const* d_in, const int* in_sizes, int n_in,
                              void* d_out, int out_size, void* d_ws, size_t ws_size,
                              hipStream_t stream) {
    const float* x  = (const float*)d_in[0];
    const float* W1 = (const float*)d_in[1];
    const float* b1 = (const float*)d_in[2];
    const float* W2 = (const float*)d_in[3];
    const float* b2 = (const float*)d_in[4];
    float* out = (float*)d_out;

    float* ai = (float*)d_ws;                          // BB*NN*D floats
    float* aj = ai + (size_t)BB * NN * D;              // BB*NN*D floats
    uint4* w2fT = (uint4*)(aj + (size_t)BB * NN * D);  // 384 uint4

    precompute_kernel<<<BB * NN / 2, 256, 0, stream>>>(x, W1, b1, W2, ai, aj, w2fT);
    pair_kernel<<<BB * NN, 256, 0, stream>>>(ai, aj, w2fT, b2, out);
}

// Round 18
// 32.869 us; speedup vs baseline: 1.0453x; 1.0453x over previous
//
#include <hip/hip_runtime.h>
#include <math.h>

#define D 40
#define NN 1024
#define BB 2

typedef __attribute__((ext_vector_type(8))) _Float16 f16x8;
typedef __attribute__((ext_vector_type(4))) float f32x4;

__device__ __forceinline__ unsigned int pk16(float a, float b) {
    return __builtin_bit_cast(unsigned int, __builtin_amdgcn_cvt_pkrtz(a, b));
}

// gelu = a - a/(exp2(a*(c1*a^2+c0))+1); 5 VALU + 2 trans
__device__ __forceinline__ float gelu_tanh(float a) {
    float u = a * a;
    float t1 = fmaf(0.10294366f, u, 2.3022083f);
    float e = __builtin_amdgcn_exp2f(a * t1);
    float r = __builtin_amdgcn_rcpf(e + 1.0f);
    return fmaf(-a, r, a);
}

// anti-remat pins
__device__ __forceinline__ void pinf(float& x) { asm volatile("" : "+v"(x)); }
__device__ __forceinline__ void pin4(float4& v) {
    asm volatile("" : "+v"(v.x), "+v"(v.y), "+v"(v.z), "+v"(v.w));
}
__device__ __forceinline__ void pin8(f16x8& v) {
    uint4 u = __builtin_bit_cast(uint4, v);
    asm volatile("" : "+v"(u.x), "+v"(u.y), "+v"(u.z), "+v"(u.w));
    v = __builtin_bit_cast(f16x8, u);
}

// build fp16x8 B-fragment: gelu(air + ajv) for 8 consecutive k
__device__ __forceinline__ f16x8 frag8(float4 a0, float4 a1, float4 x0, float4 x1) {
    float g0 = gelu_tanh(a0.x + x0.x);
    float g1 = gelu_tanh(a0.y + x0.y);
    float g2 = gelu_tanh(a0.z + x0.z);
    float g3 = gelu_tanh(a0.w + x0.w);
    float g4 = gelu_tanh(a1.x + x1.x);
    float g5 = gelu_tanh(a1.y + x1.y);
    float g6 = gelu_tanh(a1.z + x1.z);
    float g7 = gelu_tanh(a1.w + x1.w);
    return __builtin_bit_cast(f16x8,
        make_uint4(pk16(g0, g1), pk16(g2, g3), pk16(g4, g5), pk16(g6, g7)));
}

// ai = x @ W1[:D] + b1, aj = x @ W1[D:].  2 rows/block; one 40-FMA chain/thread.
__global__ __launch_bounds__(256) void precompute_kernel(
    const float* __restrict__ x, const float* __restrict__ W1,
    const float* __restrict__ b1, const float* __restrict__ W2,
    float* __restrict__ ai, float* __restrict__ aj, uint4* __restrict__ w2fT) {
    const int t = threadIdx.x;
    const int bid = blockIdx.x;
    const int r = (bid << 1) + (t >> 7);
    const int tl = t & 127;
    const float* xr = x + (size_t)r * D;

    if (tl < D) {
        const int d = tl;
        float s = b1[d];
#pragma unroll
        for (int k = 0; k < D; ++k) s = fmaf(xr[k], W1[k * D + d], s);
        ai[(size_t)r * D + d] = s;
    } else if (tl >= 64 && tl < 64 + D) {
        const int d = tl - 64;
        float s = 0.0f;
#pragma unroll
        for (int k = 0; k < D; ++k) s = fmaf(xr[k], W1[(D + k) * D + d], s);
        aj[(size_t)r * D + d] = s;
    }

    if (bid == 0 && t < 64) {
        // A = W2^T: A[m=d, k] = W2[k][d]; lane: m = l&15, k = kt*32 + (l>>4)*8 + e
        const int lr = t & 15, lg = t >> 4;
#pragma unroll
        for (int mt = 0; mt < 3; ++mt)
#pragma unroll
            for (int kt = 0; kt < 2; ++kt) {
                unsigned int u[4];
#pragma unroll
                for (int pe = 0; pe < 4; ++pe) {
                    int k0 = kt * 32 + lg * 8 + pe * 2;
                    int dd = mt * 16 + lr;
                    float v0 = (k0 < D && dd < D) ? W2[k0 * D + dd] : 0.0f;
                    float v1 = (k0 + 1 < D && dd < D) ? W2[(k0 + 1) * D + dd] : 0.0f;
                    u[pe] = pk16(v0, v1);
                }
                w2fT[(mt * 2 + kt) * 64 + t] = make_uint4(u[0], u[1], u[2], u[3]);
            }
    }
}

__global__ __launch_bounds__(256)
__attribute__((amdgpu_waves_per_eu(4)))     // min 4 waves/EU -> VGPR budget <= 128
void pair_kernel(
    const float* __restrict__ ai_g, const float* __restrict__ aj_g,
    const uint4* __restrict__ w2fT, const float* __restrict__ b2,
    float* __restrict__ out) {
    __shared__ float mbuf[224];               // 4 waves x 56 (only LDS use)

    const int t = threadIdx.x;
    const int bid = blockIdx.x;
    const int bb = bid & 1;
    const int i = NN - 1 - (bid >> 1);        // big rows first
    const int w = t >> 6;
    const int l = t & 63;
    const int lr = l & 15;
    const int lg = l >> 4;                    // 0..3
    const int idxA = lr << 2;

    // W2^T A-fragments (zero rows for k>=40 kill don't-care B slots), pinned
    f16x8 w2t[3][2];
#pragma unroll
    for (int mt = 0; mt < 3; ++mt)
#pragma unroll
        for (int kt = 0; kt < 2; ++kt) {
            w2t[mt][kt] = __builtin_bit_cast(f16x8, w2fT[(mt * 2 + kt) * 64 + l]);
            pin8(w2t[mt][kt]);
        }

    // bias for d = mt*16 + lg*4 + r (0 for d >= 40), pinned
    float bv2[3][4];
#pragma unroll
    for (int mt = 0; mt < 3; ++mt)
#pragma unroll
        for (int r = 0; r < 4; ++r) {
            int d = mt * 16 + lg * 4 + r;
            bv2[mt][r] = (d < D) ? b2[d] : 0.0f;
            pinf(bv2[mt][r]);
        }

    const float* ai_row = ai_g + ((size_t)bb * NN + i) * D;
    float4 air0 = *reinterpret_cast<const float4*>(ai_row + (lg << 3));
    float4 air1 = *reinterpret_cast<const float4*>(ai_row + (lg << 3) + 4);
    float4 ai32 = *reinterpret_cast<const float4*>(ai_row + 32 + ((l >> 5) << 2));
    pin4(air0); pin4(air1); pin4(ai32);

    const float* aj_b = aj_g + (size_t)bb * NN * D;

    // no-max softmax state: s <= ~20 so w = e^s is f32-safe (bit-validated R13-R16)
    float l_run = 0.0f;
    float o[3][4];
#pragma unroll
    for (int mt = 0; mt < 3; ++mt)
#pragma unroll
        for (int r = 0; r < 4; ++r) o[mt][r] = 0.0f;

    auto window = [&](int jbase, float4 qa0, float4 qa1, float4 qb0,
                      float4 qb1, float4 qt, bool masked) {
        // tail gelu: k = 32+kk..+3 (kk=(l>>5)*4) of j = jbase+(l&31)
        unsigned int pd0, pd1;
        {
            float g0 = gelu_tanh(ai32.x + qt.x);
            float g1 = gelu_tanh(ai32.y + qt.y);
            float g2 = gelu_tanh(ai32.z + qt.z);
            float g3 = gelu_tanh(ai32.w + qt.w);
            pd0 = pk16(g0, g1);
            pd1 = pk16(g2, g3);
        }
        uint4 tB0, tB1;
        tB0.x = __builtin_amdgcn_ds_bpermute(idxA,       pd0);
        tB0.y = __builtin_amdgcn_ds_bpermute(idxA,       pd1);
        tB0.z = __builtin_amdgcn_ds_bpermute(idxA + 128, pd0);
        tB0.w = __builtin_amdgcn_ds_bpermute(idxA + 128, pd1);
        tB1.x = __builtin_amdgcn_ds_bpermute(idxA + 64,  pd0);
        tB1.y = __builtin_amdgcn_ds_bpermute(idxA + 64,  pd1);
        tB1.z = __builtin_amdgcn_ds_bpermute(idxA + 192, pd0);
        tB1.w = __builtin_amdgcn_ds_bpermute(idxA + 192, pd1);

        f32x4 acc[3][2];
#pragma unroll
        for (int mt = 0; mt < 3; ++mt)
#pragma unroll
            for (int n = 0; n < 2; ++n)
                acc[mt][n] = (f32x4){bv2[mt][0], bv2[mt][1], bv2[mt][2], bv2[mt][3]};
        {
            f16x8 B = frag8(air0, air1, qa0, qa1);
            f16x8 Bt = __builtin_bit_cast(f16x8, tB0);
#pragma unroll
            for (int mt = 0; mt < 3; ++mt) {
                acc[mt][0] = __builtin_amdgcn_mfma_f32_16x16x32_f16(
                    w2t[mt][0], B, acc[mt][0], 0, 0, 0);
                acc[mt][0] = __builtin_amdgcn_mfma_f32_16x16x32_f16(
                    w2t[mt][1], Bt, acc[mt][0], 0, 0, 0);
            }
        }
        {
            f16x8 B = frag8(air0, air1, qb0, qb1);
            f16x8 Bt = __builtin_bit_cast(f16x8, tB1);
#pragma unroll
            for (int mt = 0; mt < 3; ++mt) {
                acc[mt][1] = __builtin_amdgcn_mfma_f32_16x16x32_f16(
                    w2t[mt][0], B, acc[mt][1], 0, 0, 0);
                acc[mt][1] = __builtin_amdgcn_mfma_f32_16x16x32_f16(
                    w2t[mt][1], Bt, acc[mt][1], 0, 0, 0);
            }
        }

        // ||p|| per j; w = e^s directly (no max shift, no rescale)
        float sv[2];
#pragma unroll
        for (int n = 0; n < 2; ++n) {
            float sq = 0.0f;
#pragma unroll
            for (int mt = 0; mt < 3; ++mt)
#pragma unroll
                for (int r = 0; r < 4; ++r)
                    sq = fmaf(acc[mt][n][r], acc[mt][n][r], sq);
            sq += __shfl_xor(sq, 16);
            sq += __shfl_xor(sq, 32);
            if (masked) {
                int j = jbase + n * 16 + lr;
                sv[n] = (j <= i) ? __builtin_amdgcn_sqrtf(sq) : -1e30f;
            } else {
                sv[n] = __builtin_amdgcn_sqrtf(sq);
            }
        }
        float w0 = __expf(sv[0]);              // masked j -> exactly 0
        float w1 = __expf(sv[1]);
        l_run += w0 + w1;
#pragma unroll
        for (int mt = 0; mt < 3; ++mt)
#pragma unroll
            for (int r = 0; r < 4; ++r)
                o[mt][r] = fmaf(w0, acc[mt][0][r], fmaf(w1, acc[mt][1][r], o[mt][r]));
    };

    // ---- full windows: no clamps, induction pointers, fixed-offset loads ----
    int jbase = w << 5;
    const float* pA = aj_b + (size_t)(jbase + lr) * D + (lg << 3);
    const float* pT = aj_b + (size_t)(jbase + (l & 31)) * D + 32 + ((l >> 5) << 2);
    for (; jbase + 31 <= i; jbase += 128) {
        float4 qa0 = *reinterpret_cast<const float4*>(pA);
        float4 qa1 = *reinterpret_cast<const float4*>(pA + 4);
        float4 qb0 = *reinterpret_cast<const float4*>(pA + 16 * D);
        float4 qb1 = *reinterpret_cast<const float4*>(pA + 16 * D + 4);
        float4 qt  = *reinterpret_cast<const float4*>(pT);
        pA += 128 * D;
        pT += 128 * D;
        window(jbase, qa0, qa1, qb0, qb1, qt, false);
    }
    // ---- at most one partial window (clamped loads, masked sv) ----
    if (jbase <= i) {
        const int j0 = min(jbase + lr, i);
        const int j1 = min(jbase + 16 + lr, i);
        const int jt = min(jbase + (l & 31), i);
        const float* r0 = aj_b + (size_t)j0 * D + (lg << 3);
        const float* r1 = aj_b + (size_t)j1 * D + (lg << 3);
        float4 qa0 = *reinterpret_cast<const float4*>(r0);
        float4 qa1 = *reinterpret_cast<const float4*>(r0 + 4);
        float4 qb0 = *reinterpret_cast<const float4*>(r1);
        float4 qb1 = *reinterpret_cast<const float4*>(r1 + 4);
        float4 qt  = *reinterpret_cast<const float4*>(
            aj_b + (size_t)jt * D + 32 + ((l >> 5) << 2));
        window(jbase, qa0, qa1, qb0, qb1, qt, true);
    }

    // ---- reduce o over the 16 j-lanes, merge 4 waves ----
#pragma unroll
    for (int mt = 0; mt < 3; ++mt)
#pragma unroll
        for (int r = 0; r < 4; ++r) {
            float v = o[mt][r];
            v += __shfl_xor(v, 1);
            v += __shfl_xor(v, 2);
            v += __shfl_xor(v, 4);
            v += __shfl_xor(v, 8);
            o[mt][r] = v;
        }
    l_run += __shfl_xor(l_run, 1);
    l_run += __shfl_xor(l_run, 2);
    l_run += __shfl_xor(l_run, 4);
    l_run += __shfl_xor(l_run, 8);

    if (lr == 0) {
#pragma unroll
        for (int mt = 0; mt < 3; ++mt)
#pragma unroll
            for (int r = 0; r < 4; ++r) {
                int d = mt * 16 + lg * 4 + r;
                if (d < D) mbuf[w * 56 + d] = o[mt][r];
            }
        if (lg == 0) mbuf[w * 56 + 48] = l_run;
    }
    __syncthreads();
    if (t < D) {
        float L = mbuf[48] + mbuf[56 + 48] + mbuf[112 + 48] + mbuf[168 + 48];
        float val = mbuf[t] + mbuf[56 + t] + mbuf[112 + t] + mbuf[168 + t];
        out[((size_t)bb * NN + i) * D + t] = val / L;
    }
}

extern "C" void kernel_launch(void* const* d_in, const int* in_sizes, int n_in,
                              void* d_out, int out_size, void* d_ws, size_t ws_size,
                              hipStream_t stream) {
    const float* x  = (const float*)d_in[0];
    const float* W1 = (const float*)d_in[1];
    const float* b1 = (const float*)d_in[2];
    const float* W2 = (const float*)d_in[3];
    const float* b2 = (const float*)d_in[4];
    float* out = (float*)d_out;

    float* ai = (float*)d_ws;                          // BB*NN*D floats
    float* aj = ai + (size_t)BB * NN * D;              // BB*NN*D floats
    uint4* w2fT = (uint4*)(aj + (size_t)BB * NN * D);  // 384 uint4

    precompute_kernel<<<BB * NN / 2, 256, 0, stream>>>(x, W1, b1, W2, ai, aj, w2fT);
    pair_kernel<<<BB * NN, 256, 0, stream>>>(ai, aj, w2fT, b2, out);
}

// Round 19
// 31.612 us; speedup vs baseline: 1.0869x; 1.0398x over previous
//
#include <hip/hip_runtime.h>
#include <math.h>

#define D 40
#define NN 1024
#define BB 2

typedef __attribute__((ext_vector_type(8))) _Float16 f16x8;
typedef __attribute__((ext_vector_type(4))) float f32x4;
typedef __attribute__((ext_vector_type(2))) float f32x2;

__device__ __forceinline__ unsigned int pk16(float a, float b) {
    return __builtin_bit_cast(unsigned int, __builtin_amdgcn_cvt_pkrtz(a, b));
}

__device__ __forceinline__ f32x2 lo2(float4 v) { return (f32x2){v.x, v.y}; }
__device__ __forceinline__ f32x2 hi2(float4 v) { return (f32x2){v.z, v.w}; }

// packed-pair gelu: g = s - s/(exp2(s*(c1*s^2+c0))+1)
// VALU ops are f32x2 (v_pk_*); exp2/rcp remain scalar trans.
// overflow: e->inf -> r=0 -> g=s; underflow: e->0 -> r=1 -> g=0 (both correct)
__device__ __forceinline__ unsigned int gelu2pk(f32x2 s) {
    f32x2 u = s * s;
    f32x2 t1 = u * 0.10294366f + 2.3022083f;     // pk_fma
    f32x2 z = s * t1;                            // pk_mul
    f32x2 e = { __builtin_amdgcn_exp2f(z.x), __builtin_amdgcn_exp2f(z.y) };
    e = e + 1.0f;                                // pk_add
    f32x2 r = { __builtin_amdgcn_rcpf(e.x), __builtin_amdgcn_rcpf(e.y) };
    f32x2 g = s - s * r;                         // pk_fma(-s, r, s)
    return pk16(g.x, g.y);
}

// anti-remat pins
__device__ __forceinline__ void pinf(float& x) { asm volatile("" : "+v"(x)); }
__device__ __forceinline__ void pin4(float4& v) {
    asm volatile("" : "+v"(v.x), "+v"(v.y), "+v"(v.z), "+v"(v.w));
}
__device__ __forceinline__ void pin8(f16x8& v) {
    uint4 u = __builtin_bit_cast(uint4, v);
    asm volatile("" : "+v"(u.x), "+v"(u.y), "+v"(u.z), "+v"(u.w));
    v = __builtin_bit_cast(f16x8, u);
}
__device__ __forceinline__ void pinv4(f32x4& v) {
    asm volatile("" : "+v"(v.x), "+v"(v.y), "+v"(v.z), "+v"(v.w));
}

// build fp16x8 B-fragment: gelu(air + ajv) for 8 consecutive k (4 packed pairs)
__device__ __forceinline__ f16x8 frag8(float4 a0, float4 a1, float4 x0, float4 x1) {
    uint4 Bu;
    Bu.x = gelu2pk(lo2(a0) + lo2(x0));
    Bu.y = gelu2pk(hi2(a0) + hi2(x0));
    Bu.z = gelu2pk(lo2(a1) + lo2(x1));
    Bu.w = gelu2pk(hi2(a1) + hi2(x1));
    return __builtin_bit_cast(f16x8, Bu);
}

// ai = x @ W1[:D] + b1, aj = x @ W1[D:].  2 rows/block; one 40-FMA chain/thread.
__global__ __launch_bounds__(256) void precompute_kernel(
    const float* __restrict__ x, const float* __restrict__ W1,
    const float* __restrict__ b1, const float* __restrict__ W2,
    float* __restrict__ ai, float* __restrict__ aj, uint4* __restrict__ w2fT) {
    const int t = threadIdx.x;
    const int bid = blockIdx.x;
    const int r = (bid << 1) + (t >> 7);
    const int tl = t & 127;
    const float* xr = x + (size_t)r * D;

    if (tl < D) {
        const int d = tl;
        float s = b1[d];
#pragma unroll
        for (int k = 0; k < D; ++k) s = fmaf(xr[k], W1[k * D + d], s);
        ai[(size_t)r * D + d] = s;
    } else if (tl >= 64 && tl < 64 + D) {
        const int d = tl - 64;
        float s = 0.0f;
#pragma unroll
        for (int k = 0; k < D; ++k) s = fmaf(xr[k], W1[(D + k) * D + d], s);
        aj[(size_t)r * D + d] = s;
    }

    if (bid == 0 && t < 64) {
        // A = W2^T: A[m=d, k] = W2[k][d]; lane: m = l&15, k = kt*32 + (l>>4)*8 + e
        const int lr = t & 15, lg = t >> 4;
#pragma unroll
        for (int mt = 0; mt < 3; ++mt)
#pragma unroll
            for (int kt = 0; kt < 2; ++kt) {
                unsigned int u[4];
#pragma unroll
                for (int pe = 0; pe < 4; ++pe) {
                    int k0 = kt * 32 + lg * 8 + pe * 2;
                    int dd = mt * 16 + lr;
                    float v0 = (k0 < D && dd < D) ? W2[k0 * D + dd] : 0.0f;
                    float v1 = (k0 + 1 < D && dd < D) ? W2[(k0 + 1) * D + dd] : 0.0f;
                    u[pe] = pk16(v0, v1);
                }
                w2fT[(mt * 2 + kt) * 64 + t] = make_uint4(u[0], u[1], u[2], u[3]);
            }
    }
}

__global__ __launch_bounds__(256)
__attribute__((amdgpu_waves_per_eu(4)))     // min 4 waves/EU -> VGPR budget <= 128
void pair_kernel(
    const float* __restrict__ ai_g, const float* __restrict__ aj_g,
    const uint4* __restrict__ w2fT, const float* __restrict__ b2,
    float* __restrict__ out) {
    __shared__ float mbuf[224];               // 4 waves x 56 (only LDS use)

    const int t = threadIdx.x;
    const int bid = blockIdx.x;
    const int bb = bid & 1;
    const int i = NN - 1 - (bid >> 1);        // big rows first
    const int w = t >> 6;
    const int l = t & 63;
    const int lr = l & 15;
    const int lg = l >> 4;                    // 0..3
    const int idxA = lr << 2;

    // W2^T A-fragments (zero rows for k>=40 kill don't-care B slots), pinned
    f16x8 w2t[3][2];
#pragma unroll
    for (int mt = 0; mt < 3; ++mt)
#pragma unroll
        for (int kt = 0; kt < 2; ++kt) {
            w2t[mt][kt] = __builtin_bit_cast(f16x8, w2fT[(mt * 2 + kt) * 64 + l]);
            pin8(w2t[mt][kt]);
        }

    // bias vector for d = mt*16 + lg*4 + r (0 for d >= 40), pinned
    f32x4 bv4[3];
#pragma unroll
    for (int mt = 0; mt < 3; ++mt) {
#pragma unroll
        for (int r = 0; r < 4; ++r) {
            int d = mt * 16 + lg * 4 + r;
            bv4[mt][r] = (d < D) ? b2[d] : 0.0f;
        }
        pinv4(bv4[mt]);
    }

    const float* ai_row = ai_g + ((size_t)bb * NN + i) * D;
    float4 air0 = *reinterpret_cast<const float4*>(ai_row + (lg << 3));
    float4 air1 = *reinterpret_cast<const float4*>(ai_row + (lg << 3) + 4);
    float4 ai32 = *reinterpret_cast<const float4*>(ai_row + 32 + ((l >> 5) << 2));
    pin4(air0); pin4(air1); pin4(ai32);

    const float* aj_b = aj_g + (size_t)bb * NN * D;

    // no-max softmax state: s <= ~20 so w = e^s is f32-safe (bit-validated R13-R18)
    float l_run = 0.0f;
    f32x4 o4[3];
#pragma unroll
    for (int mt = 0; mt < 3; ++mt) o4[mt] = (f32x4){0.0f, 0.0f, 0.0f, 0.0f};

    auto window = [&](int jbase, float4 qa0, float4 qa1, float4 qb0,
                      float4 qb1, float4 qt, bool masked) {
        // tail gelu: k = 32+kk..+3 (kk=(l>>5)*4) of j = jbase+(l&31), packed pairs
        unsigned int pd0 = gelu2pk(lo2(ai32) + lo2(qt));
        unsigned int pd1 = gelu2pk(hi2(ai32) + hi2(qt));
        uint4 tB0, tB1;
        tB0.x = __builtin_amdgcn_ds_bpermute(idxA,       pd0);
        tB0.y = __builtin_amdgcn_ds_bpermute(idxA,       pd1);
        tB0.z = __builtin_amdgcn_ds_bpermute(idxA + 128, pd0);
        tB0.w = __builtin_amdgcn_ds_bpermute(idxA + 128, pd1);
        tB1.x = __builtin_amdgcn_ds_bpermute(idxA + 64,  pd0);
        tB1.y = __builtin_amdgcn_ds_bpermute(idxA + 64,  pd1);
        tB1.z = __builtin_amdgcn_ds_bpermute(idxA + 192, pd0);
        tB1.w = __builtin_amdgcn_ds_bpermute(idxA + 192, pd1);

        f32x4 acc[3][2];
#pragma unroll
        for (int mt = 0; mt < 3; ++mt)
#pragma unroll
            for (int n = 0; n < 2; ++n)
                acc[mt][n] = bv4[mt];
        {
            f16x8 B = frag8(air0, air1, qa0, qa1);
            f16x8 Bt = __builtin_bit_cast(f16x8, tB0);
#pragma unroll
            for (int mt = 0; mt < 3; ++mt) {
                acc[mt][0] = __builtin_amdgcn_mfma_f32_16x16x32_f16(
                    w2t[mt][0], B, acc[mt][0], 0, 0, 0);
                acc[mt][0] = __builtin_amdgcn_mfma_f32_16x16x32_f16(
                    w2t[mt][1], Bt, acc[mt][0], 0, 0, 0);
            }
        }
        {
            f16x8 B = frag8(air0, air1, qb0, qb1);
            f16x8 Bt = __builtin_bit_cast(f16x8, tB1);
#pragma unroll
            for (int mt = 0; mt < 3; ++mt) {
                acc[mt][1] = __builtin_amdgcn_mfma_f32_16x16x32_f16(
                    w2t[mt][0], B, acc[mt][1], 0, 0, 0);
                acc[mt][1] = __builtin_amdgcn_mfma_f32_16x16x32_f16(
                    w2t[mt][1], Bt, acc[mt][1], 0, 0, 0);
            }
        }

        // ||p|| per j via packed fma; w = e^s directly (no max shift)
        float sv[2];
#pragma unroll
        for (int n = 0; n < 2; ++n) {
            f32x4 sq4 = acc[0][n] * acc[0][n];
            sq4 = acc[1][n] * acc[1][n] + sq4;   // pk_fma x2
            sq4 = acc[2][n] * acc[2][n] + sq4;
            float sq = (sq4.x + sq4.y) + (sq4.z + sq4.w);
            sq += __shfl_xor(sq, 16);
            sq += __shfl_xor(sq, 32);
            if (masked) {
                int j = jbase + n * 16 + lr;
                sv[n] = (j <= i) ? __builtin_amdgcn_sqrtf(sq) : -1e30f;
            } else {
                sv[n] = __builtin_amdgcn_sqrtf(sq);
            }
        }
        float w0 = __expf(sv[0]);              // masked j -> exactly 0
        float w1 = __expf(sv[1]);
        l_run += w0 + w1;
#pragma unroll
        for (int mt = 0; mt < 3; ++mt) {
            o4[mt] = acc[mt][1] * w1 + o4[mt];   // pk_fma x2
            o4[mt] = acc[mt][0] * w0 + o4[mt];
        }
    };

    // ---- full windows: no clamps, induction pointers, fixed-offset loads ----
    int jbase = w << 5;
    const float* pA = aj_b + (size_t)(jbase + lr) * D + (lg << 3);
    const float* pT = aj_b + (size_t)(jbase + (l & 31)) * D + 32 + ((l >> 5) << 2);
    for (; jbase + 31 <= i; jbase += 128) {
        float4 qa0 = *reinterpret_cast<const float4*>(pA);
        float4 qa1 = *reinterpret_cast<const float4*>(pA + 4);
        float4 qb0 = *reinterpret_cast<const float4*>(pA + 16 * D);
        float4 qb1 = *reinterpret_cast<const float4*>(pA + 16 * D + 4);
        float4 qt  = *reinterpret_cast<const float4*>(pT);
        pA += 128 * D;
        pT += 128 * D;
        window(jbase, qa0, qa1, qb0, qb1, qt, false);
    }
    // ---- at most one partial window (clamped loads, masked sv) ----
    if (jbase <= i) {
        const int j0 = min(jbase + lr, i);
        const int j1 = min(jbase + 16 + lr, i);
        const int jt = min(jbase + (l & 31), i);
        const float* r0 = aj_b + (size_t)j0 * D + (lg << 3);
        const float* r1 = aj_b + (size_t)j1 * D + (lg << 3);
        float4 qa0 = *reinterpret_cast<const float4*>(r0);
        float4 qa1 = *reinterpret_cast<const float4*>(r0 + 4);
        float4 qb0 = *reinterpret_cast<const float4*>(r1);
        float4 qb1 = *reinterpret_cast<const float4*>(r1 + 4);
        float4 qt  = *reinterpret_cast<const float4*>(
            aj_b + (size_t)jt * D + 32 + ((l >> 5) << 2));
        window(jbase, qa0, qa1, qb0, qb1, qt, true);
    }

    // ---- reduce o over the 16 j-lanes, merge 4 waves ----
#pragma unroll
    for (int mt = 0; mt < 3; ++mt)
#pragma unroll
        for (int r = 0; r < 4; ++r) {
            float v = o4[mt][r];
            v += __shfl_xor(v, 1);
            v += __shfl_xor(v, 2);
            v += __shfl_xor(v, 4);
            v += __shfl_xor(v, 8);
            o4[mt][r] = v;
        }
    l_run += __shfl_xor(l_run, 1);
    l_run += __shfl_xor(l_run, 2);
    l_run += __shfl_xor(l_run, 4);
    l_run += __shfl_xor(l_run, 8);

    if (lr == 0) {
#pragma unroll
        for (int mt = 0; mt < 3; ++mt)
#pragma unroll
            for (int r = 0; r < 4; ++r) {
                int d = mt * 16 + lg * 4 + r;
                if (d < D) mbuf[w * 56 + d] = o4[mt][r];
            }
        if (lg == 0) mbuf[w * 56 + 48] = l_run;
    }
    __syncthreads();
    if (t < D) {
        float L = mbuf[48] + mbuf[56 + 48] + mbuf[112 + 48] + mbuf[168 + 48];
        float val = mbuf[t] + mbuf[56 + t] + mbuf[112 + t] + mbuf[168 + t];
        out[((size_t)bb * NN + i) * D + t] = val / L;
    }
}

extern "C" void kernel_launch(void* const* d_in, const int* in_sizes, int n_in,
                              void* d_out, int out_size, void* d_ws, size_t ws_size,
                              hipStream_t stream) {
    const float* x  = (const float*)d_in[0];
    const float* W1 = (const float*)d_in[1];
    const float* b1 = (const float*)d_in[2];
    const float* W2 = (const float*)d_in[3];
    const float* b2 = (const float*)d_in[4];
    float* out = (float*)d_out;

    float* ai = (float*)d_ws;                          // BB*NN*D floats
    float* aj = ai + (size_t)BB * NN * D;              // BB*NN*D floats
    uint4* w2fT = (uint4*)(aj + (size_t)BB * NN * D);  // 384 uint4

    precompute_kernel<<<BB * NN / 2, 256, 0, stream>>>(x, W1, b1, W2, ai, aj, w2fT);
    pair_kernel<<<BB * NN, 256, 0, stream>>>(ai, aj, w2fT, b2, out);
}